// Round 4
// baseline (366.145 us; speedup 1.0000x reference)
//
#include <hip/hip_runtime.h>
#include <hip/hip_bf16.h>

// TransformerXL relative position embedding, fused.
// out[b,n,u,w,c] = dot(Q[b,u,w,n,:], K[b,u,c,n,:])
//                + (0 <= c-w < 128 ? dot(Q[b,u,w,n,:], E[c-w,n,:]) : 0)
// Dims: B=4 U=32 W=128 N=8 H=64 C=255 F=128, D=512.
// Block = (b,u,n,cblk): 128 output cols per block -> LDS 68.5 KB -> 2 blocks/CU.

typedef __bf16 bf16x8 __attribute__((ext_vector_type(8)));
typedef float f32x4 __attribute__((ext_vector_type(4)));

#define MFMA16(a, b, c) __builtin_amdgcn_mfma_f32_16x16x32_bf16((a), (b), (c), 0, 0, 0)

__device__ __forceinline__ unsigned short f2bf(float x) {
  unsigned u = __float_as_uint(x);
  u += 0x7FFFu + ((u >> 16) & 1u);   // round-to-nearest-even
  return (unsigned short)(u >> 16);
}
__device__ __forceinline__ float bf2f(unsigned short x) {
  return __uint_as_float((unsigned)x << 16);
}

// ---------------- E precompute: PK (512,8,64) -> E bf16 [N=8][F=128][H=64] ----------------
// 256 blocks (f, half) x 256 threads: full-GPU version.
__global__ __launch_bounds__(256) void compute_E(const float* __restrict__ pk,
                                                 unsigned short* __restrict__ E) {
  const int f = blockIdx.x >> 1, half = blockIdx.x & 1;
  const int t = threadIdx.x;            // 0..255
  const int nh = half * 256 + t;
  __shared__ float sv[256], cv[256];
  {
    const float L = 9.210340371976184f / 255.0f;  // log(10000)/255
    float ang = (float)(127 - f) * expf(-L * (float)t);
    sv[t] = sinf(ang);
    cv[t] = cosf(ang);
  }
  __syncthreads();
  float acc = 0.f;
#pragma unroll 8
  for (int i = 0; i < 256; ++i)
    acc = fmaf(sv[i], pk[i * 512 + nh], fmaf(cv[i], pk[(i + 256) * 512 + nh], acc));
  const int n = nh >> 6, h = nh & 63;
  E[(n * 128 + f) * 64 + h] = f2bf(acc);
}

// ---------------- main fused kernel: one block per (b,u,n,cblk) ----------------
// LDS: Qs[128][72] bf16 (18.4K), Un[128][72] bf16 (18.4K, E then K-half),
//      bds[128][130] bf16 (33.3K). Total 68.5 KB -> 2 blocks/CU, 16 waves/CU.
__global__ __launch_bounds__(512, 4) void txl_main(const float* __restrict__ Q,
                                                   const float* __restrict__ K,
                                                   const unsigned short* __restrict__ E,
                                                   float* __restrict__ out) {
  __shared__ unsigned short Qs[128 * 72];
  __shared__ unsigned short Un[128 * 72];
  __shared__ unsigned short bds[128 * 130];

  const int tid = threadIdx.x;
  const int n  = blockIdx.x & 7;
  const int bu = blockIdx.x >> 3;       // b*32 + u
  const int c0base = (int)blockIdx.y * 128;

  // ---- stage Q (128x64 f32 -> bf16) ----
  const float* gq = Q + (size_t)bu * (128 * 512) + n * 64;
#pragma unroll
  for (int i = 0; i < 4; ++i) {
    int fi = i * 512 + tid;             // 0..2047 float4s
    int row = fi >> 4, c4 = fi & 15;
    float4 v = *(const float4*)(gq + row * 512 + c4 * 4);
    ushort4 r;
    r.x = f2bf(v.x); r.y = f2bf(v.y); r.z = f2bf(v.z); r.w = f2bf(v.w);
    *(ushort4*)(&Qs[row * 72 + c4 * 4]) = r;
  }
  // ---- stage E slice (128x64 bf16) into Un ----
#pragma unroll
  for (int i = 0; i < 2; ++i) {
    int t2 = i * 512 + tid;             // 0..1023 uint4s
    uint4 v = *((const uint4*)(E + n * (128 * 64)) + t2);
    *(uint4*)(&Un[(t2 >> 3) * 72 + (t2 & 7) * 8]) = v;
  }
  // ---- issue K loads to registers (rows c0base..c0base+127, guard c<255) ----
  const float* gk = K + (size_t)bu * (255 * 512) + n * 64;
  float4 kr[4];
#pragma unroll
  for (int i = 0; i < 4; ++i) {
    int fi = i * 512 + tid;             // 0..2047 float4s over 128 rows
    int r = fi >> 4, c4 = fi & 15;
    int c = c0base + r;
    if (c < 255) kr[i] = *(const float4*)(gk + (size_t)c * 512 + c4 * 4);
    else { kr[i].x = 0.f; kr[i].y = 0.f; kr[i].z = 0.f; kr[i].w = 0.f; }
  }
  __syncthreads();

  const int l = tid & 63, wv = tid >> 6;
  const int a = l & 15, g = l >> 4;
  const int r0 = wv * 16;
  const int arow = (r0 + a) * 72 + g * 8;
  bf16x8 qa0 = *(const bf16x8*)&Qs[arow];
  bf16x8 qa1 = *(const bf16x8*)&Qs[arow + 32];

  // ---- bd = Q @ E^T (128x128) -> bds (bf16) ----
#pragma unroll
  for (int ft = 0; ft < 8; ++ft) {
    const int f0 = ft * 16;
    const int brow = (f0 + a) * 72 + g * 8;
    bf16x8 eb0 = *(const bf16x8*)&Un[brow];
    bf16x8 eb1 = *(const bf16x8*)&Un[brow + 32];
    f32x4 acc = {0.f, 0.f, 0.f, 0.f};
    acc = MFMA16(qa0, eb0, acc);
    acc = MFMA16(qa1, eb1, acc);
    const int wrow = r0 + g * 4;
#pragma unroll
    for (int j = 0; j < 4; ++j)
      bds[(wrow + j) * 130 + f0 + a] = f2bf(acc[j]);
  }
  __syncthreads();   // all Es reads done; bds visible after next barrier

  // ---- convert K regs -> Un (overwrites E slice) ----
#pragma unroll
  for (int i = 0; i < 4; ++i) {
    int fi = i * 512 + tid;
    int r = fi >> 4, c4 = fi & 15;
    ushort4 rr;
    rr.x = f2bf(kr[i].x); rr.y = f2bf(kr[i].y);
    rr.z = f2bf(kr[i].z); rr.w = f2bf(kr[i].w);
    *(ushort4*)(&Un[r * 72 + c4 * 4]) = rr;
  }
  __syncthreads();

  // ---- ac = Q @ K^T (128 x 128 cols) with fused shift-add + store ----
  const int b = bu >> 5, u = bu & 31;
  float* gout = out + (size_t)((b * 8 + n) * 32 + u) * (128 * 255);
#pragma unroll
  for (int ct = 0; ct < 8; ++ct) {
    const int cc0 = ct * 16;
    const int brow = (cc0 + a) * 72 + g * 8;
    bf16x8 kb0 = *(const bf16x8*)&Un[brow];
    bf16x8 kb1 = *(const bf16x8*)&Un[brow + 32];
    f32x4 acc = {0.f, 0.f, 0.f, 0.f};
    acc = MFMA16(qa0, kb0, acc);
    acc = MFMA16(qa1, kb1, acc);
    const int c = c0base + cc0 + a;
#pragma unroll
    for (int j = 0; j < 4; ++j) {
      const int row = r0 + g * 4 + j;
      const int f = c - row;            // relative position
      float val = acc[j];
      if ((unsigned)f < 128u) val += bf2f(bds[row * 130 + f]);
      if (c < 255) gout[(size_t)row * 255 + c] = val;
    }
  }
}

extern "C" void kernel_launch(void* const* d_in, const int* in_sizes, int n_in,
                              void* d_out, int out_size, void* d_ws, size_t ws_size,
                              hipStream_t stream) {
  const float* q  = (const float*)d_in[0];   // (4,32,128,8,64)
  const float* k  = (const float*)d_in[1];   // (4,32,255,8,64)
  const float* pk = (const float*)d_in[2];   // (512,8,64)
  float* out = (float*)d_out;                // (4,8,32,128,255)
  unsigned short* E = (unsigned short*)d_ws; // bf16 [8][128][64] = 128 KB

  compute_E<<<dim3(256), dim3(256), 0, stream>>>(pk, E);
  txl_main<<<dim3(1024, 2), dim3(512), 0, stream>>>(q, k, E, out);
}

// Round 5
// 236.043 us; speedup vs baseline: 1.5512x; 1.5512x over previous
//
#include <hip/hip_runtime.h>
#include <hip/hip_bf16.h>

// TransformerXL relative position embedding, fused.
// out[b,n,u,w,c] = dot(Q[b,u,w,n,:], K[b,u,c,n,:])
//                + (0 <= c-w < 128 ? dot(Q[b,u,w,n,:], E[c-w,n,:]) : 0)
// E[f,n,h] = sum_i sin((127-f)*t_i)*PK[i,n,h] + cos((127-f)*t_i)*PK[i+256,n,h]
// Dims: B=4 U=32 W=128 N=8 H=64 C=255 F=128, D=512.

typedef __bf16 bf16x8 __attribute__((ext_vector_type(8)));
typedef float f32x4 __attribute__((ext_vector_type(4)));

#define MFMA16(a, b, c) __builtin_amdgcn_mfma_f32_16x16x32_bf16((a), (b), (c), 0, 0, 0)

__device__ __forceinline__ unsigned short f2bf(float x) {
  unsigned u = __float_as_uint(x);
  u += 0x7FFFu + ((u >> 16) & 1u);   // round-to-nearest-even
  return (unsigned short)(u >> 16);
}

// ---------------- E precompute: PK (512,8,64) -> E bf16 [N=8][F=128][H=64] ----------------
// v2: K-parallel. Block per (f,n) = 1024 blocks x 256 threads; thread (h, ks)
// covers 64 of 256 timescales -> 128 coalesced loads/thread, LDS 4-way reduce.
__global__ __launch_bounds__(256) void compute_E(const float* __restrict__ pk,
                                                 unsigned short* __restrict__ E) {
  const int f = blockIdx.x >> 3;      // 0..127
  const int n = blockIdx.x & 7;       // 0..7
  const int t = threadIdx.x;          // 0..255
  __shared__ float sv[256], cv[256];
  __shared__ float part[4 * 68];
  {
    const float L = 9.210340371976184f / 255.0f;  // log(10000)/255
    float ang = (float)(127 - f) * expf(-L * (float)t);
    sv[t] = sinf(ang);
    cv[t] = cosf(ang);
  }
  __syncthreads();
  const int h = t & 63, ks = t >> 6;
  const float* p0 = pk + n * 64 + h;
  float acc = 0.f;
#pragma unroll 8
  for (int j = 0; j < 64; ++j) {
    int k = ks * 64 + j;
    acc = fmaf(sv[k], p0[k * 512], fmaf(cv[k], p0[(k + 256) * 512], acc));
  }
  part[ks * 68 + h] = acc;
  __syncthreads();
  if (t < 64) {
    float s = part[t] + part[68 + t] + part[2 * 68 + t] + part[3 * 68 + t];
    E[(n * 128 + f) * 64 + t] = f2bf(s);
  }
}

// ---------------- main fused kernel: one block per (b,u,n) ----------------
// (R3-proven structure, 81 us.)
// LDS: Qs[128][72] bf16, Ks[256][72] bf16, Es[128][72] bf16, bds[128][129] f32
__global__ __launch_bounds__(512) void txl_main(const float* __restrict__ Q,
                                                const float* __restrict__ K,
                                                const unsigned short* __restrict__ E,
                                                float* __restrict__ out) {
  __shared__ unsigned short Qs[128 * 72];
  __shared__ unsigned short Ks[256 * 72];
  __shared__ unsigned short Es[128 * 72];
  __shared__ float bds[128 * 129];

  const int tid = threadIdx.x;
  const int blk = blockIdx.x;
  const int n  = blk & 7;
  const int bu = blk >> 3;  // b*32 + u

  // ---- stage Q (128x64 f32 -> bf16) ----
  const float* gq = Q + (size_t)bu * (128 * 512) + n * 64;
#pragma unroll
  for (int i = 0; i < 4; ++i) {
    int fi = i * 512 + tid;          // 0..2047 float4s
    int row = fi >> 4, c4 = fi & 15;
    float4 v = *(const float4*)(gq + row * 512 + c4 * 4);
    ushort4 r;
    r.x = f2bf(v.x); r.y = f2bf(v.y); r.z = f2bf(v.z); r.w = f2bf(v.w);
    *(ushort4*)(&Qs[row * 72 + c4 * 4]) = r;
  }
  // ---- stage K (255x64 f32 -> bf16; row 255 zeroed) ----
  const float* gk = K + (size_t)bu * (255 * 512) + n * 64;
#pragma unroll
  for (int i = 0; i < 8; ++i) {
    int fi = i * 512 + tid;          // 0..4095 float4s, rows 0..255
    int row = fi >> 4, c4 = fi & 15;
    float4 v;
    if (row < 255) v = *(const float4*)(gk + row * 512 + c4 * 4);
    else { v.x = 0.f; v.y = 0.f; v.z = 0.f; v.w = 0.f; }
    ushort4 r;
    r.x = f2bf(v.x); r.y = f2bf(v.y); r.z = f2bf(v.z); r.w = f2bf(v.w);
    *(ushort4*)(&Ks[row * 72 + c4 * 4]) = r;
  }
  // ---- stage E slice (128x64 bf16): 1024 uint4 chunks, 2 per thread ----
#pragma unroll
  for (int i = 0; i < 2; ++i) {
    int t2 = i * 512 + tid;          // 0..1023
    uint4 v = *((const uint4*)(E + n * (128 * 64)) + t2);
    *(uint4*)(&Es[(t2 >> 3) * 72 + (t2 & 7) * 8]) = v;
  }
  __syncthreads();

  const int l = tid & 63, wv = tid >> 6;
  const int a = l & 15, g = l >> 4;

  // ---- bd = Q @ E^T (128x128) -> bds ----
  {
    const int r0 = wv * 16;
    const int arow = (r0 + a) * 72 + g * 8;
    bf16x8 qa0 = *(const bf16x8*)&Qs[arow];
    bf16x8 qa1 = *(const bf16x8*)&Qs[arow + 32];
#pragma unroll
    for (int ft = 0; ft < 8; ++ft) {
      const int f0 = ft * 16;
      const int brow = (f0 + a) * 72 + g * 8;
      bf16x8 eb0 = *(const bf16x8*)&Es[brow];
      bf16x8 eb1 = *(const bf16x8*)&Es[brow + 32];
      f32x4 acc = {0.f, 0.f, 0.f, 0.f};
      acc = MFMA16(qa0, eb0, acc);
      acc = MFMA16(qa1, eb1, acc);
      const int wrow = r0 + g * 4;
#pragma unroll
      for (int j = 0; j < 4; ++j)
        bds[(wrow + j) * 129 + f0 + a] = acc[j];
    }
  }
  __syncthreads();

  // ---- ac = Q @ K^T with fused shift-add + store ----
  const int b = bu >> 5, u = bu & 31;
  float* gout = out + (size_t)((b * 8 + n) * 32 + u) * (128 * 255);
#pragma unroll
  for (int rt = 0; rt < 8; ++rt) {
    const int r0 = rt * 16;
    const int arow = (r0 + a) * 72 + g * 8;
    bf16x8 qa0 = *(const bf16x8*)&Qs[arow];
    bf16x8 qa1 = *(const bf16x8*)&Qs[arow + 32];
#pragma unroll
    for (int ct = 0; ct < 2; ++ct) {
      const int c0 = wv * 32 + ct * 16;
      const int brow = (c0 + a) * 72 + g * 8;
      bf16x8 kb0 = *(const bf16x8*)&Ks[brow];
      bf16x8 kb1 = *(const bf16x8*)&Ks[brow + 32];
      f32x4 acc = {0.f, 0.f, 0.f, 0.f};
      acc = MFMA16(qa0, kb0, acc);
      acc = MFMA16(qa1, kb1, acc);
      const int c = c0 + a;
#pragma unroll
      for (int j = 0; j < 4; ++j) {
        const int row = r0 + g * 4 + j;
        const int f = c - row;          // relative position
        float val = acc[j];
        if ((unsigned)f < 128u) val += bds[row * 129 + f];
        if (c < 255) gout[(size_t)row * 255 + c] = val;
      }
    }
  }
}

extern "C" void kernel_launch(void* const* d_in, const int* in_sizes, int n_in,
                              void* d_out, int out_size, void* d_ws, size_t ws_size,
                              hipStream_t stream) {
  const float* q  = (const float*)d_in[0];   // (4,32,128,8,64)
  const float* k  = (const float*)d_in[1];   // (4,32,255,8,64)
  const float* pk = (const float*)d_in[2];   // (512,8,64)
  float* out = (float*)d_out;                // (4,8,32,128,255)
  unsigned short* E = (unsigned short*)d_ws; // bf16 [8][128][64] = 128 KB

  compute_E<<<dim3(1024), dim3(256), 0, stream>>>(pk, E);
  txl_main<<<dim3(1024), dim3(512), 0, stream>>>(q, k, E, out);
}